// Round 1
// baseline (188.643 us; speedup 1.0000x reference)
//
#include <hip/hip_runtime.h>
#include <math.h>

// Problem constants (from reference)
#define NPTS   131072
#define DIMC   256      // 16*16 output channels per point
#define YD     9
#define NPATHS 96
#define NPATH0 32
#define HID    64
#define NREG   65       // <= HID+1 relu-sign regions over t in [0,inf)
#define QSTR   18       // coeffs per (region, c): 9 for t*Y, 9 for Y

typedef float f32x4 __attribute__((ext_vector_type(4)));

// ws layout (floats):
//   Q    : [NREG][QSTR][DIMC] = 299520   (TRANSPOSED this round: v-major,
//          channel-minor, so main-kernel coeff loads are lane-coalesced)
//   xflip: [HID]
//   k2   : [DIMC]
//
// Q[j][v][c]: v in [0,18). v = y   -> P coeff (multiplies t*Y[y])
//                          v = 9+y -> D coeff (multiplies Y[y])

// ---------------------------------------------------------------------------
// Kernel A: per-region coefficient precompute.
// R5 rebuild: 8-lane groups do coalesced 128B-chunk reads of M1 rows +
// __shfl_xor reduce (prev: per-thread rows -> every dwordx4 split into 64
// L2 transactions). Grid = NREG*4 row-chunks = 260 blocks. sv/sc hoisted
// into registers outside the row loop.
// ---------------------------------------------------------------------------
__global__ __launch_bounds__(256) void precompute_kernel(
    const float* __restrict__ W1, const float* __restrict__ b1,
    const float* __restrict__ W2, const float* __restrict__ b2,
    const float* __restrict__ M1, const float* __restrict__ M2,
    const float* __restrict__ wgt,
    float* __restrict__ Q, float* __restrict__ xout, float* __restrict__ k2out)
{
    const int j    = blockIdx.x >> 2;   // region
    const int rblk = blockIdx.x & 3;    // row-chunk of the 2304 (c,y) rows
    const int tid  = threadIdx.x;
    __shared__ __align__(16) float sx[HID];
    __shared__ __align__(16) float sa[HID], sb[HID];
    __shared__ __align__(16) float ssa[HID], ssb[HID];
    __shared__ __align__(16) float sv[NPATHS], sc[NPATHS];

    if (tid < HID) {
        float a = W1[tid], b = b1[tid];
        sa[tid] = a; sb[tid] = b;
        // knot in (0,inf) exists iff a,b have opposite (strict) signs
        bool flips = (a > 0.f && b < 0.f) || (a < 0.f && b > 0.f);
        sx[tid] = flips ? (-b / a) : __builtin_inff();
    }
    __syncthreads();
    if (tid < HID) {
        float a = sa[tid], b = sb[tid], xh = sx[tid];
        int rank = 0;
        for (int k = 0; k < HID; ++k) {
            float xk = sx[k];
            rank += (xk < xh || (xk == xh && k < tid)) ? 1 : 0;
        }
        bool base = (b > 0.f) || (b == 0.f && a > 0.f);  // pattern at t->0+
        bool sig  = base ^ (rank < j);
        ssa[tid] = sig ? a : 0.f;
        ssb[tid] = sig ? b : 0.f;
    }
    __syncthreads();
    if (tid < NPATHS) {
        float vv = 0.f, cc = 0.f;
        for (int h = 0; h < HID; ++h) {
            float w2 = W2[h * NPATHS + tid];
            vv += ssa[h] * w2;
            cc += ssb[h] * w2;
        }
        sv[tid] = vv;
        sc[tid] = cc + b2[tid];
    }
    __syncthreads();

    {   // 8-lane groups: group g handles row = c*9+y; lane covers 12 w's
        const int g    = tid >> 3;      // 32 groups
        const int lane = tid & 7;
        const float4 v0 = *(const float4*)(sv + lane * 4);
        const float4 v1 = *(const float4*)(sv + lane * 4 + 32);
        const float4 v2 = *(const float4*)(sv + lane * 4 + 64);
        const float4 d0 = *(const float4*)(sc + lane * 4);
        const float4 d1 = *(const float4*)(sc + lane * 4 + 32);
        const float4 d2 = *(const float4*)(sc + lane * 4 + 64);
        const int row0 = rblk * (2304 / 4);
        for (int it = 0; it < (2304 / 4) / 32; ++it) {
            const int row = row0 + it * 32 + g;           // = c*9 + y
            const float* mrow = M1 + (size_t)row * NPATHS + lane * 4;
            float4 m0 = *(const float4*)(mrow);
            float4 m1 = *(const float4*)(mrow + 32);
            float4 m2 = *(const float4*)(mrow + 64);
            float p = m0.x*v0.x + m0.y*v0.y + m0.z*v0.z + m0.w*v0.w
                    + m1.x*v1.x + m1.y*v1.y + m1.z*v1.z + m1.w*v1.w
                    + m2.x*v2.x + m2.y*v2.y + m2.z*v2.z + m2.w*v2.w;
            float d = m0.x*d0.x + m0.y*d0.y + m0.z*d0.z + m0.w*d0.w
                    + m1.x*d1.x + m1.y*d1.y + m1.z*d1.z + m1.w*d1.w
                    + m2.x*d2.x + m2.y*d2.y + m2.z*d2.z + m2.w*d2.w;
            #pragma unroll
            for (int off = 1; off < 8; off <<= 1) {
                p += __shfl_xor(p, off, 64);
                d += __shfl_xor(d, off, 64);
            }
            if (lane == 0) {
                const int c = row / 9;
                const int y = row - c * 9;
                Q[((size_t)j * QSTR + y)     * DIMC + c] = p;
                Q[((size_t)j * QSTR + 9 + y) * DIMC + c] = d;
            }
        }
    }

    if (blockIdx.x == 0) {
        if (tid < HID) xout[tid] = sx[tid];
        float s = 0.f;
        #pragma unroll
        for (int k = 0; k < NPATH0; ++k) s += M2[tid * NPATH0 + k] * wgt[k];
        k2out[tid] = s;
    }
}

// ---------------------------------------------------------------------------
// Kernel B: main. Block = 256 threads, 64 points.
// R5 changes vs R4-best:
//  - xflip staged through LDS (was: 64 serial wave-uniform global loads on
//    the barrier-exposed critical path)
//  - cfs loads lane-coalesced from transposed Q (was: 64-way divergent,
//    64 L2 txns per dwordx4)
//  - speculative region-0 cfs prefetch issued before the barrier; data has
//    b1==0 => jj==0 everywhere, reload path keeps general correctness
//  - launch_bounds(256,3): 3 blocks/CU for latency hiding (VGPR cap 170;
//    hot live set ~= cfs[72]+misc, fits)
// NOTE: still NO unroll pragma on the p-loop — full unroll hoisted ~80
// ds_reads and spilled (R1-R3 ~200us).
// ---------------------------------------------------------------------------
__global__ __launch_bounds__(256, 3) void main_kernel(
    const float* __restrict__ r, const float* __restrict__ Q,
    const float* __restrict__ xflip, const float* __restrict__ k2,
    float* __restrict__ out)
{
    __shared__ __align__(16) float qArr[64 * 20];
    __shared__ __align__(16) float sxf[64];
    __shared__ int sUni, sJJ0;
    const int tid = threadIdx.x;
    const int n0  = blockIdx.x * 64;
    const int cg  = tid & 63;
    const int pg  = tid >> 6;
    const int c0i = cg * 4;

    if (tid < 64) {
        sxf[tid] = xflip[tid];              // one coalesced 256B load
        const int n = n0 + tid;
        float rx = r[(size_t)n * 3 + 0];
        float ry = r[(size_t)n * 3 + 1];
        float rz = r[(size_t)n * 3 + 2];
        float t  = sqrtf(rx * rx + ry * ry + rz * rz);
        float rcp = 1.f / fmaxf(t, 1e-12f);
        float ux = rx * rcp, uy = ry * rcp, uz = rz * rcp;
        const float c0 = 0.28209479177387814f;
        const float c1 = 0.4886025119029199f;
        const float c2 = 1.0925484305920792f;
        float Y[9];
        Y[0] = c0;
        Y[1] = c1 * uy;
        Y[2] = c1 * uz;
        Y[3] = c1 * ux;
        Y[4] = c2 * ux * uy;
        Y[5] = c2 * uy * uz;
        Y[6] = 0.31539156525252005f * (3.f * uz * uz - 1.f);
        Y[7] = c2 * ux * uz;
        Y[8] = 0.5462742152960396f * (ux * ux - uy * uy);
        float* q = qArr + tid * 20;
        #pragma unroll
        for (int y = 0; y < 9; ++y) { q[y] = t * Y[y]; q[9 + y] = Y[y]; }
        q[19] = (t > 0.f) ? 1.f : 0.f;
        // jj from LDS knots (broadcast reads, same-wave RAW -> no barrier)
        int jj = 0;
        #pragma unroll
        for (int h4 = 0; h4 < 16; ++h4) {
            float4 x4 = ((const float4*)sxf)[h4];
            jj += (x4.x < t ? 1 : 0) + (x4.y < t ? 1 : 0)
                + (x4.z < t ? 1 : 0) + (x4.w < t ? 1 : 0);
        }
        q[18] = (float)jj;
        // wave 0 fully active: detect region-uniformity
        int jj0 = __shfl(jj, 0, 64);
        unsigned long long bal = __ballot(jj == jj0);
        if (tid == 0) { sUni = (bal == 0xFFFFFFFFFFFFFFFFULL) ? 1 : 0; sJJ0 = jj0; }
    }

    // Speculative coefficient prefetch for region 0: coalesced, latency
    // hides under phase 1 + barrier. cfs[v*4+k] = coeff v of channel c0i+k.
    float cfs[72];
    {
        const float4* cb = (const float4*)Q + cg;       // Q[0][v][c0i..+3]
        #pragma unroll
        for (int v = 0; v < 18; ++v) {
            float4 t4 = cb[v * 64];
            cfs[v * 4 + 0] = t4.x; cfs[v * 4 + 1] = t4.y;
            cfs[v * 4 + 2] = t4.z; cfs[v * 4 + 3] = t4.w;
        }
    }
    __syncthreads();

    const float4 k2v = *(const float4*)(k2 + c0i);
    const int pbeg = pg * 16;

    if (sUni) {
        if (sJJ0 != 0) {    // speculation missed: reload (still coalesced)
            const float4* cb = (const float4*)(Q + (size_t)sJJ0 * QSTR * DIMC) + cg;
            #pragma unroll
            for (int v = 0; v < 18; ++v) {
                float4 t4 = cb[v * 64];
                cfs[v * 4 + 0] = t4.x; cfs[v * 4 + 1] = t4.y;
                cfs[v * 4 + 2] = t4.z; cfs[v * 4 + 3] = t4.w;
            }
        }
        for (int p = pbeg; p < pbeg + 16; ++p) {
            const float4* qv = (const float4*)(qArr + p * 20);
            float4 a0 = qv[0], a1 = qv[1], a2 = qv[2], a3 = qv[3], a4 = qv[4];
            const float qs[18] = { a0.x, a0.y, a0.z, a0.w,  a1.x, a1.y, a1.z, a1.w,
                                   a2.x, a2.y, a2.z, a2.w,  a3.x, a3.y, a3.z, a3.w,
                                   a4.x, a4.y };
            float acc0 = 0.f, acc1 = 0.f, acc2 = 0.f, acc3 = 0.f;
            #pragma unroll
            for (int v = 0; v < 18; ++v) {
                acc0 += qs[v] * cfs[v * 4 + 0];
                acc1 += qs[v] * cfs[v * 4 + 1];
                acc2 += qs[v] * cfs[v * 4 + 2];
                acc3 += qs[v] * cfs[v * 4 + 3];
            }
            const bool msk = (a4.w != 0.f);
            f32x4 o;
            o.x = msk ? acc0 : k2v.x;
            o.y = msk ? acc1 : k2v.y;
            o.z = msk ? acc2 : k2v.z;
            o.w = msk ? acc3 : k2v.w;
            __builtin_nontemporal_store(o, (f32x4*)(out + (size_t)(n0 + p) * DIMC + c0i));
        }
    } else {
        // ---- fallback: mixed regions in block (general correctness) ----
        int curj = 0;       // cfs currently holds region 0
        for (int p = pbeg; p < pbeg + 16; ++p) {
            const float4* qv = (const float4*)(qArr + p * 20);
            float4 a0 = qv[0], a1 = qv[1], a2 = qv[2], a3 = qv[3], a4 = qv[4];
            int jj = (int)a4.z;
            if (jj != curj) {               // wave-uniform (p identical in-wave)
                curj = jj;
                const float4* cb = (const float4*)(Q + (size_t)jj * QSTR * DIMC) + cg;
                #pragma unroll
                for (int v = 0; v < 18; ++v) {
                    float4 t4 = cb[v * 64];
                    cfs[v * 4 + 0] = t4.x; cfs[v * 4 + 1] = t4.y;
                    cfs[v * 4 + 2] = t4.z; cfs[v * 4 + 3] = t4.w;
                }
            }
            const float qs[18] = { a0.x, a0.y, a0.z, a0.w,  a1.x, a1.y, a1.z, a1.w,
                                   a2.x, a2.y, a2.z, a2.w,  a3.x, a3.y, a3.z, a3.w,
                                   a4.x, a4.y };
            float acc0 = 0.f, acc1 = 0.f, acc2 = 0.f, acc3 = 0.f;
            #pragma unroll
            for (int v = 0; v < 18; ++v) {
                acc0 += qs[v] * cfs[v * 4 + 0];
                acc1 += qs[v] * cfs[v * 4 + 1];
                acc2 += qs[v] * cfs[v * 4 + 2];
                acc3 += qs[v] * cfs[v * 4 + 3];
            }
            const bool msk = (a4.w != 0.f);
            f32x4 o;
            o.x = msk ? acc0 : k2v.x;
            o.y = msk ? acc1 : k2v.y;
            o.z = msk ? acc2 : k2v.z;
            o.w = msk ? acc3 : k2v.w;
            __builtin_nontemporal_store(o, (f32x4*)(out + (size_t)(n0 + p) * DIMC + c0i));
        }
    }
}

extern "C" void kernel_launch(void* const* d_in, const int* in_sizes, int n_in,
                              void* d_out, int out_size, void* d_ws, size_t ws_size,
                              hipStream_t stream)
{
    const float* r   = (const float*)d_in[0];
    const float* M1  = (const float*)d_in[1];
    const float* M2  = (const float*)d_in[2];
    const float* wgt = (const float*)d_in[3];
    const float* W1  = (const float*)d_in[4];
    const float* b1  = (const float*)d_in[5];
    const float* W2  = (const float*)d_in[6];
    const float* b2  = (const float*)d_in[7];
    float* out = (float*)d_out;

    float* ws = (float*)d_ws;
    float* Q  = ws;
    float* xf = ws + (size_t)NREG * DIMC * QSTR;
    float* k2 = xf + HID;

    precompute_kernel<<<NREG * 4, 256, 0, stream>>>(W1, b1, W2, b2, M1, M2, wgt, Q, xf, k2);
    main_kernel<<<NPTS / 64, 256, 0, stream>>>(r, Q, xf, k2, out);
}